// Round 10
// baseline (103.295 us; speedup 1.0000x reference)
//
#include <hip/hip_runtime.h>

// GAT, round 9: (1) k_h epilogue via swapped MFMA operands -> D^T layout ->
// direct row-major 8B h stores (no LDS repack, no extra barriers, no bank
// conflicts); (2) k_srt bitonic sort replaced by O(N^2/P) counting-rank
// (broadcast b128 reads, no per-stage barriers).
// Algorithm: e_ij = leaky(s1_i + s2_j) rank-1 + monotone kink; sort j by s2,
// negative branch is a prefix per row:
//   out_i = c1_i*(U_N - U_{k_i}) + c2_i*V_{k_i};  O(N^2 F) -> O(N F).

typedef unsigned short u16;
typedef unsigned int   u32;
typedef unsigned long long u64;
typedef float  f32x4  __attribute__((ext_vector_type(4)));
typedef __bf16 bf16x8 __attribute__((ext_vector_type(8)));
typedef __bf16 bf16x4 __attribute__((ext_vector_type(4)));

#define NB    64
#define NENT  1024
#define FD    256
#define NROWS (NB * NENT)
#define ALPHA 0.2f

typedef __attribute__((address_space(1))) const void* gas_ptr;
typedef __attribute__((address_space(3))) void*       las_ptr;
__device__ __forceinline__ void gload16(const void* g, void* l) {
  __builtin_amdgcn_global_load_lds((gas_ptr)g, (las_ptr)l, 16, 0, 0);
}

// ---------------- k_wa: Wa1 = W@a1, Wa2 = W@a2 (fp32 exact) ----------------
__global__ __launch_bounds__(256) void k_wa(const float* __restrict__ W,
                                            const float* __restrict__ a,
                                            float* __restrict__ Wa1,
                                            float* __restrict__ Wa2) {
  const int k = blockIdx.x, f = threadIdx.x;
  const float w = W[(size_t)k * FD + f];
  float p1 = w * a[f];
  float p2 = w * a[FD + f];
#pragma unroll
  for (int off = 1; off < 64; off <<= 1) {
    p1 += __shfl_xor(p1, off, 64);
    p2 += __shfl_xor(p2, off, 64);
  }
  __shared__ float r1[4], r2[4];
  const int wv = f >> 6, lane = f & 63;
  if (lane == 0) { r1[wv] = p1; r2[wv] = p2; }
  __syncthreads();
  if (f == 0) {
    Wa1[k] = r1[0] + r1[1] + r1[2] + r1[3];
    Wa2[k] = r2[0] + r2[1] + r2[2] + r2[3];
  }
}

// ---------------- k_wt: Wt[f][k] = bf16(W[k][f]) ----------------
__global__ __launch_bounds__(256) void k_wt(const float* __restrict__ W,
                                            u16* __restrict__ Wt) {
  __shared__ float tile[64][65];
  const int t = threadIdx.x;
  const int ki = blockIdx.x >> 2, fi = blockIdx.x & 3;
  const int k0 = ki * 64, f0 = fi * 64;
  const int r = t >> 4, c4 = (t & 15) * 4;
#pragma unroll
  for (int it = 0; it < 4; ++it) {
    const int row = r + it * 16;
    float4 v = *(const float4*)&W[(size_t)(k0 + row) * FD + f0 + c4];
    tile[row][c4 + 0] = v.x; tile[row][c4 + 1] = v.y;
    tile[row][c4 + 2] = v.z; tile[row][c4 + 3] = v.w;
  }
  __syncthreads();
#pragma unroll
  for (int it = 0; it < 4; ++it) {
    const int fr = r + it * 16;
    bf16x4 pk;
    pk[0] = (__bf16)tile[c4 + 0][fr]; pk[1] = (__bf16)tile[c4 + 1][fr];
    pk[2] = (__bf16)tile[c4 + 2][fr]; pk[3] = (__bf16)tile[c4 + 3][fr];
    *(bf16x4*)&Wt[(size_t)(f0 + fr) * FD + k0 + c4] = pk;
  }
}

// -------- k_h: h = bf16(x@W) row-major, s1, s2 (256x256 tile, dbuf) --------
// MFMA operands SWAPPED: acc = mfma(B_frag, A_frag) = (A@B)^T fragmentwise,
// so each lane's 4 regs are 4 consecutive h-columns of one x-row -> direct
// 8B row-major global stores, no repack.
__global__ __launch_bounds__(512, 2) void k_h(
    const float* __restrict__ x, const u16* __restrict__ Wt,
    const float* __restrict__ Wa1g, const float* __restrict__ Wa2g,
    u16* __restrict__ h, float* __restrict__ s1, float* __restrict__ s2) {
  __shared__ __align__(16) u16 Ab[2][4][256][8];   // 32 KB
  __shared__ __align__(16) u16 Bb[2][4][256][8];   // 32 KB
  __shared__ float wa1[FD], wa2[FD];
  const int t = threadIdx.x;
  const int lane = t & 63, wv = t >> 6;
  const int wr = wv >> 2, wc = wv & 3;          // wave tile 128x64
  const int g16 = lane >> 4, c15 = lane & 15;
  const int p = blockIdx.x;
  const int lb = (p & 7) * 32 + (p >> 3);       // XCD-chunked
  const int rT = lb * 256;
  if (t < FD) { wa1[t] = Wa1g[t]; wa2[t] = Wa2g[t]; }
  const int row = t >> 1, half = t & 1;         // staging: 2 thr/row, 16 k
  const float* xsrc = x + (size_t)(rT + row) * FD + half * 16;
  float p1 = 0.f, p2 = 0.f;
  f32x4 acc[8][4];
  const f32x4 vz = {0.f, 0.f, 0.f, 0.f};
#pragma unroll
  for (int i = 0; i < 8; ++i)
#pragma unroll
    for (int j = 0; j < 4; ++j) acc[i][j] = vz;

  auto stage = [&](int nb, int kc, const float4& f0, const float4& f1,
                   const float4& f2, const float4& f3) {
    const int k0n = kc * 32;
    const int d0 = t;
    gload16(Wt + (size_t)(d0 & 255) * FD + k0n + (d0 >> 8) * 8,
            (char*)(&Bb[nb][0][0][0]) + d0 * 16);
    const int d1 = t + 512;
    gload16(Wt + (size_t)(d1 & 255) * FD + k0n + (d1 >> 8) * 8,
            (char*)(&Bb[nb][0][0][0]) + d1 * 16);
    bf16x8 w0, w1;
    w0[0] = (__bf16)f0.x; w0[1] = (__bf16)f0.y;
    w0[2] = (__bf16)f0.z; w0[3] = (__bf16)f0.w;
    w0[4] = (__bf16)f1.x; w0[5] = (__bf16)f1.y;
    w0[6] = (__bf16)f1.z; w0[7] = (__bf16)f1.w;
    w1[0] = (__bf16)f2.x; w1[1] = (__bf16)f2.y;
    w1[2] = (__bf16)f2.z; w1[3] = (__bf16)f2.w;
    w1[4] = (__bf16)f3.x; w1[5] = (__bf16)f3.y;
    w1[6] = (__bf16)f3.z; w1[7] = (__bf16)f3.w;
    *(bf16x8*)&Ab[nb][half * 2][row][0] = w0;
    *(bf16x8*)&Ab[nb][half * 2 + 1][row][0] = w1;
    const int kb = k0n + half * 16;
    p1 += f0.x*wa1[kb+ 0] + f0.y*wa1[kb+ 1] + f0.z*wa1[kb+ 2] + f0.w*wa1[kb+ 3]
        + f1.x*wa1[kb+ 4] + f1.y*wa1[kb+ 5] + f1.z*wa1[kb+ 6] + f1.w*wa1[kb+ 7]
        + f2.x*wa1[kb+ 8] + f2.y*wa1[kb+ 9] + f2.z*wa1[kb+10] + f2.w*wa1[kb+11]
        + f3.x*wa1[kb+12] + f3.y*wa1[kb+13] + f3.z*wa1[kb+14] + f3.w*wa1[kb+15];
    p2 += f0.x*wa2[kb+ 0] + f0.y*wa2[kb+ 1] + f0.z*wa2[kb+ 2] + f0.w*wa2[kb+ 3]
        + f1.x*wa2[kb+ 4] + f1.y*wa2[kb+ 5] + f1.z*wa2[kb+ 6] + f1.w*wa2[kb+ 7]
        + f2.x*wa2[kb+ 8] + f2.y*wa2[kb+ 9] + f2.z*wa2[kb+10] + f2.w*wa2[kb+11]
        + f3.x*wa2[kb+12] + f3.y*wa2[kb+13] + f3.z*wa2[kb+14] + f3.w*wa2[kb+15];
  };
  auto mfma_step = [&](int cb) {
    bf16x8 bfv[4];
#pragma unroll
    for (int fj = 0; fj < 4; ++fj)
      bfv[fj] = *(const bf16x8*)&Bb[cb][g16][wc * 64 + fj * 16 + c15][0];
#pragma unroll
    for (int fi = 0; fi < 8; ++fi) {
      bf16x8 af = *(const bf16x8*)&Ab[cb][g16][wr * 128 + fi * 16 + c15][0];
#pragma unroll
      for (int fj = 0; fj < 4; ++fj)
        acc[fi][fj] = __builtin_amdgcn_mfma_f32_16x16x32_bf16(
            bfv[fj], af, acc[fi][fj], 0, 0, 0);   // SWAPPED: D^T fragments
    }
  };

  float4 xc0 = *(const float4*)(xsrc +  0);
  float4 xc1 = *(const float4*)(xsrc +  4);
  float4 xc2 = *(const float4*)(xsrc +  8);
  float4 xc3 = *(const float4*)(xsrc + 12);
  float4 xb0 = *(const float4*)(xsrc + 32);
  float4 xb1 = *(const float4*)(xsrc + 36);
  float4 xb2 = *(const float4*)(xsrc + 40);
  float4 xb3 = *(const float4*)(xsrc + 44);
  float4 xa0 = *(const float4*)(xsrc + 64);
  float4 xa1 = *(const float4*)(xsrc + 68);
  float4 xa2 = *(const float4*)(xsrc + 72);
  float4 xa3 = *(const float4*)(xsrc + 76);
  __syncthreads();                 // wa1/wa2 visible
  stage(0, 0, xc0, xc1, xc2, xc3);
  __syncthreads();                 // A[0] written, B[0] arrived
#pragma unroll 1
  for (int ks2 = 0; ks2 < 4; ++ks2) {
    stage(1, 2 * ks2 + 1, xb0, xb1, xb2, xb3);
    if (2 * ks2 + 3 < 8) {
      const float* s = xsrc + (2 * ks2 + 3) * 32;
      xb0 = *(const float4*)(s);      xb1 = *(const float4*)(s + 4);
      xb2 = *(const float4*)(s + 8);  xb3 = *(const float4*)(s + 12);
    }
    mfma_step(0);
    __syncthreads();
    if (2 * ks2 + 2 < 8) {
      stage(0, 2 * ks2 + 2, xa0, xa1, xa2, xa3);
      if (2 * ks2 + 4 < 8) {
        const float* s = xsrc + (2 * ks2 + 4) * 32;
        xa0 = *(const float4*)(s);      xa1 = *(const float4*)(s + 4);
        xa2 = *(const float4*)(s + 8);  xa3 = *(const float4*)(s + 12);
      }
    }
    mfma_step(1);
    __syncthreads();
  }
  // s1/s2: reduce 2 k-halves
  p1 += __shfl_xor(p1, 1, 64);
  p2 += __shfl_xor(p2, 1, 64);
  if (half == 0) { s1[rT + row] = p1; s2[rT + row] = p2; }
  // epilogue: direct row-major stores. Swapped-operand D layout: lane
  // (g16,c15) reg r holds h[rT+wr*128+fi*16+c15][wc*64+fj*16+4*g16+r].
#pragma unroll
  for (int fi = 0; fi < 8; ++fi) {
    const int xrow = rT + wr * 128 + fi * 16 + c15;
#pragma unroll
    for (int fj = 0; fj < 4; ++fj) {
      const int fcol = wc * 64 + fj * 16 + 4 * g16;
      bf16x4 pk;
      pk[0] = (__bf16)acc[fi][fj][0]; pk[1] = (__bf16)acc[fi][fj][1];
      pk[2] = (__bf16)acc[fi][fj][2]; pk[3] = (__bf16)acc[fi][fj][3];
      *(bf16x4*)&h[(size_t)xrow * FD + fcol] = pk;
    }
  }
}

// -------- k_srt: per-batch counting-rank sort + scans + coefs + buckets ----
__global__ __launch_bounds__(512) void k_srt(
    const float* __restrict__ s1, const float* __restrict__ s2,
    float* __restrict__ e2D, float* __restrict__ e2aD,
    float* __restrict__ c1D, float* __restrict__ c2D,
    u16* __restrict__ pidD, u16* __restrict__ iolD, u16* __restrict__ iblD) {
  __shared__ __align__(16) u64  kp[1024];
  __shared__ __align__(16) float key[1024];
  __shared__ __align__(16) u16   pid[1024];
  __shared__ __align__(16) float e2l[1024], e2al[1024];
  __shared__ __align__(16) float Su[1032], Sv[1032];
  __shared__ __align__(16) float c1l[1024], c2l[1024];
  __shared__ __align__(16) u32   cnt[1025];
  __shared__ __align__(16) u16   ibl[1032];
  __shared__ __align__(16) u16   iol[1024];
  __shared__ float UpS[8];
  const int t = threadIdx.x;
  const int b = blockIdx.x;
  const int w = t >> 6, lane = t & 63;

  // 1) packed keys (monotone f32->u32 map, index in low bits: strict order)
  auto packkey = [&](int j) -> u64 {
    float v = s2[(size_t)b * NENT + j];
    u32 u = __builtin_bit_cast(u32, v);
    u32 su = u ^ (u32)(((int)u >> 31) | 0x80000000);
    u64 pk = ((u64)su << 32) | (u32)j;
    kp[j] = pk;
    return pk;
  };
  const u64 myA = packkey(t);
  const u64 myB = packkey(t + 512);
  __syncthreads();
  // 2) counting rank: broadcast b128 reads, 4 u64 compares per iter
  int rA = 0, rB = 0;
#pragma unroll 4
  for (int j = 0; j < 1024; j += 2) {
    u64 pr[2];
    *(uint4*)pr = *(const uint4*)&kp[j];
    rA += (pr[0] < myA) + (pr[1] < myA);
    rB += (pr[0] < myB) + (pr[1] < myB);
  }
  // 3) scatter into sorted arrays + exp
  auto emit_sorted = [&](u64 v, int r) {
    u32 su = (u32)(v >> 32);
    u32 ub = (su & 0x80000000u) ? (su ^ 0x80000000u) : ~su;
    float kv = __builtin_bit_cast(float, ub);
    key[r] = kv;
    pid[r] = (u16)(v & 0xFFFFu);
    e2l[r] = __expf(kv);
    e2al[r] = __expf(ALPHA * kv);
  };
  emit_sorted(myA, rA);
  emit_sorted(myB, rB);
  __syncthreads();
  // 4) scans (exclusive + total)
  auto scanx = [&](const float* src, float* dst) {
    float a = src[2 * t], bb = src[2 * t + 1];
    float s = a + bb;
    float inc = s;
#pragma unroll
    for (int d = 1; d < 64; d <<= 1) {
      float o = __shfl_up(inc, d, 64);
      if (lane >= d) inc += o;
    }
    if (lane == 63) UpS[w] = inc;
    __syncthreads();
    float woff = 0.f;
#pragma unroll
    for (int w2 = 0; w2 < 8; ++w2) { float pv = UpS[w2]; if (w2 < w) woff += pv; }
    float P = woff + inc - s;
    dst[2 * t] = P; dst[2 * t + 1] = P + a;
    if (t == 511) dst[1024] = P + s;
    __syncthreads();
  };
  scanx(e2l, Su);
  scanx(e2al, Sv);
  // 5) per-i coefs + k_i
  const float s2max = key[1023];
  const float SuN = Su[1024];
  int kfA, kfB;
  cnt[t] = 0; cnt[t + 512] = 0;
  if (t == 0) cnt[1024] = 0;
  __syncthreads();
#pragma unroll
  for (int hi = 0; hi < 2; ++hi) {
    const int i = t + hi * 512;
    const float s1v = s1[(size_t)b * NENT + i];
    const float th = -s1v;
    int kf = 0;
#pragma unroll
    for (int d = 1024; d >= 1; d >>= 1)
      if (kf + d <= 1024 && key[kf + d - 1] < th) kf += d;
    const float qm = s1v + s2max;
    const float m = fmaxf(qm, ALPHA * qm);
    const float en1 = __expf(fminf(s1v - m, 80.f));
    const float en2 = __expf(fminf(ALPHA * s1v - m, 80.f));
    const float Z = en1 * (SuN - Su[kf]) + en2 * Sv[kf];
    const float rZ = 1.f / Z;
    c1l[i] = en1 * rZ; c2l[i] = en2 * rZ;
    if (hi == 0) kfA = kf; else kfB = kf;
    atomicAdd(&cnt[kf], 1u);
  }
  __syncthreads();
  // 6) exclusive scan of cnt -> ibl; zero cnt for cursors (incl bucket 1024)
  {
    float a = (float)cnt[2 * t], bb = (float)cnt[2 * t + 1];
    cnt[2 * t] = 0; cnt[2 * t + 1] = 0;
    if (t == 0) cnt[1024] = 0;
    float s = a + bb;
    float inc = s;
#pragma unroll
    for (int d = 1; d < 64; d <<= 1) {
      float o = __shfl_up(inc, d, 64);
      if (lane >= d) inc += o;
    }
    if (lane == 63) UpS[w] = inc;
    __syncthreads();
    float woff = 0.f;
#pragma unroll
    for (int w2 = 0; w2 < 8; ++w2) { float pv = UpS[w2]; if (w2 < w) woff += pv; }
    float P = woff + inc - s;
    ibl[2 * t] = (u16)P; ibl[2 * t + 1] = (u16)(P + a);
    if (t == 511) ibl[1024] = (u16)(P + s);
  }
  __syncthreads();
  // 7) scatter i's bucketed by k_i (CSR); defensive clamp
  {
    int pos = (int)ibl[kfA] + (int)atomicAdd(&cnt[kfA], 1u);
    pos = pos < 1023 ? pos : 1023;
    iol[pos] = (u16)t;
    int posB = (int)ibl[kfB] + (int)atomicAdd(&cnt[kfB], 1u);
    posB = posB < 1023 ? posB : 1023;
    iol[posB] = (u16)(t + 512);
  }
  __syncthreads();
  // 8) write descriptor (coalesced)
  const size_t ob = (size_t)b * NENT;
  e2D [ob + t] = e2l[t];  e2D [ob + t + 512] = e2l[t + 512];
  e2aD[ob + t] = e2al[t]; e2aD[ob + t + 512] = e2al[t + 512];
  c1D [ob + t] = c1l[t];  c1D [ob + t + 512] = c1l[t + 512];
  c2D [ob + t] = c2l[t];  c2D [ob + t + 512] = c2l[t + 512];
  *(u32*)&pidD[ob + 2 * t] = *(const u32*)&pid[2 * t];
  *(u32*)&iolD[ob + 2 * t] = *(const u32*)&iol[2 * t];
  *(u32*)&iblD[(size_t)b * 1040 + 2 * t] = *(const u32*)&ibl[2 * t];
  if (t == 0) iblD[(size_t)b * 1040 + 1024] = ibl[1024];
}

// -------- k_blk: 64-row block sums of e2*h, e2a*h over sorted order --------
__global__ __launch_bounds__(256) void k_blk(
    const u16* __restrict__ h, const u16* __restrict__ pidD,
    const float* __restrict__ e2D, const float* __restrict__ e2aD,
    float* __restrict__ Ublk, float* __restrict__ Vblk) {
  __shared__ u16 pids[64];
  __shared__ float e2s[64], e2as[64];
  const int t = threadIdx.x;            // col
  const int q = blockIdx.x, b = blockIdx.y;
  const int rb = q * 64;
  if (t < 64) pids[t] = pidD[(size_t)b * NENT + rb + t];
  else if (t < 128) e2s[t - 64] = e2D[(size_t)b * NENT + rb + t - 64];
  else if (t < 192) e2as[t - 128] = e2aD[(size_t)b * NENT + rb + t - 128];
  __syncthreads();
  const u16* hb = h + (size_t)b * NENT * FD + t;
  float U = 0.f, V = 0.f;
  float ha[8], hc[8];
  auto ld8 = [&](float* dv, int r) {
#pragma unroll
    for (int u = 0; u < 8; ++u) {
      u32 raw = hb[(size_t)pids[r + u] * FD];
      dv[u] = __builtin_bit_cast(float, raw << 16);
    }
  };
  ld8(ha, 0);
#pragma unroll 1
  for (int g = 0; g < 4; ++g) {
    ld8(hc, g * 16 + 8);
#pragma unroll
    for (int u = 0; u < 8; ++u) {
      U += e2s[g * 16 + u] * ha[u]; V += e2as[g * 16 + u] * ha[u];
    }
    if (g < 3) ld8(ha, g * 16 + 16);
#pragma unroll
    for (int u = 0; u < 8; ++u) {
      U += e2s[g * 16 + 8 + u] * hc[u]; V += e2as[g * 16 + 8 + u] * hc[u];
    }
  }
  Ublk[((size_t)b * 16 + q) * FD + t] = U;
  Vblk[((size_t)b * 16 + q) * FD + t] = V;
}

// -------- k_emit: table-offset scan (64 rows/wave) + threshold emission ----
__global__ __launch_bounds__(256) void k_emit(
    const u16* __restrict__ h, const u16* __restrict__ pidD,
    const float* __restrict__ e2D, const float* __restrict__ e2aD,
    const float* __restrict__ c1D, const float* __restrict__ c2D,
    const u16* __restrict__ iolD, const u16* __restrict__ iblD,
    const float* __restrict__ Ublk, const float* __restrict__ Vblk,
    float* __restrict__ out) {
  __shared__ __align__(16) float c1l[1024], c2l[1024];
  __shared__ __align__(16) u16 iol[1024];
  __shared__ __align__(16) float e2s[256], e2as[256];
  __shared__ __align__(16) u16 pids[256];
  __shared__ __align__(16) u16 iblS[260];
  const int t = threadIdx.x;
  const int bx = blockIdx.x, b = blockIdx.y;
  const int cg = bx & 3, rq = bx >> 2;
  const int w = t >> 6, lane = t & 63;
  const size_t ob = (size_t)b * NENT;
  *(float4*)&c1l[4 * t] = *(const float4*)&c1D[ob + 4 * t];
  *(float4*)&c2l[4 * t] = *(const float4*)&c2D[ob + 4 * t];
  *(uint2*)&iol[4 * t] = *(const uint2*)&iolD[ob + 4 * t];
  e2s[t]  = e2D[ob + rq * 256 + t];
  e2as[t] = e2aD[ob + rq * 256 + t];
  pids[t] = pidD[ob + rq * 256 + t];
  iblS[t] = iblD[(size_t)b * 1040 + rq * 256 + t];
  if (t == 0) iblS[256] = iblD[(size_t)b * 1040 + rq * 256 + 256];
  __syncthreads();
  const int col = cg * 64 + lane;
  const int qstart = rq * 4 + w;
  float Uoff = 0.f, Voff = 0.f, UN = 0.f, VN = 0.f;
#pragma unroll
  for (int q = 0; q < 16; ++q) {
    float uu = Ublk[((size_t)b * 16 + q) * FD + col];
    float vv = Vblk[((size_t)b * 16 + q) * FD + col];
    if (q < qstart) { Uoff += uu; Voff += vv; }
    UN += uu; VN += vv;
  }
  const u16* hb = h + ob * FD + col;
  float U = Uoff, V = Voff;
  float ha[8], hc[8];
  auto ld8 = [&](float* dv, int lr) {
#pragma unroll
    for (int u = 0; u < 8; ++u) {
      u32 raw = hb[(size_t)pids[lr + u] * FD];
      dv[u] = __builtin_bit_cast(float, raw << 16);
    }
  };
  const int lr0 = w * 64;
  ld8(ha, lr0);
#pragma unroll 1
  for (int g = 0; g < 4; ++g) {
    const int lb0 = lr0 + g * 16;
    ld8(hc, lb0 + 8);
#pragma unroll
    for (int u = 0; u < 8; ++u) {
      const int lr = lb0 + u;
      const int e0 = iblS[lr], e1 = iblS[lr + 1];
      for (int idx = e0; idx < e1; ++idx) {
        const int i = iol[idx];
        out[(ob + i) * FD + col] = c1l[i] * (UN - U) + c2l[i] * V;
      }
      U += e2s[lr] * ha[u]; V += e2as[lr] * ha[u];
    }
    if (g < 3) ld8(ha, lb0 + 16);
#pragma unroll
    for (int u = 0; u < 8; ++u) {
      const int lr = lb0 + 8 + u;
      const int e0 = iblS[lr], e1 = iblS[lr + 1];
      for (int idx = e0; idx < e1; ++idx) {
        const int i = iol[idx];
        out[(ob + i) * FD + col] = c1l[i] * (UN - U) + c2l[i] * V;
      }
      U += e2s[lr] * hc[u]; V += e2as[lr] * hc[u];
    }
  }
  if (rq == 3 && w == 3) {   // final bucket k_i == 1024 (U==UN, V==VN here)
    const int e0 = iblS[256];
    for (int idx = e0; idx < NENT; ++idx) {
      const int i = iol[idx];
      out[(ob + i) * FD + col] = c1l[i] * (UN - U) + c2l[i] * V;
    }
  }
}

extern "C" void kernel_launch(void* const* d_in, const int* in_sizes, int n_in,
                              void* d_out, int out_size, void* d_ws, size_t ws_size,
                              hipStream_t stream) {
  const float* x = (const float*)d_in[0];
  const float* W = (const float*)d_in[1];
  const float* a = (const float*)d_in[2];
  float* out = (float*)d_out;

  char* ws = (char*)d_ws;
  u16*   h    = (u16*)ws;                          // 32 MB
  float* s1   = (float*)(ws + (size_t)33554432);   // 256 KB
  float* s2   = s1 + NROWS;                        // 256 KB
  float* Wa1  = s2 + NROWS;                        // 1 KB
  float* Wa2  = Wa1 + FD;                          // 1 KB
  u16*   Wt   = (u16*)(Wa2 + FD);                  // 128 KB
  float* e2D  = (float*)((char*)Wt + 131072);      // 256 KB
  float* e2aD = e2D + NROWS;                       // 256 KB
  float* c1D  = e2aD + NROWS;                      // 256 KB
  float* c2D  = c1D + NROWS;                       // 256 KB
  u16*   pidD = (u16*)(c2D + NROWS);               // 128 KB
  u16*   iolD = pidD + NROWS;                      // 128 KB
  u16*   iblD = iolD + NROWS;                      // ~133 KB
  float* Ublk = (float*)((char*)iblD + 1040 * NB * 2); // 1 MB
  float* Vblk = Ublk + NB * 16 * FD;                   // 1 MB (~38 MB total)

  k_wa<<<dim3(256), dim3(256), 0, stream>>>(W, a, Wa1, Wa2);
  k_wt<<<dim3(16), dim3(256), 0, stream>>>(W, Wt);
  k_h<<<dim3(256), dim3(512), 0, stream>>>(x, Wt, Wa1, Wa2, h, s1, s2);
  k_srt<<<dim3(NB), dim3(512), 0, stream>>>(s1, s2, e2D, e2aD, c1D, c2D,
                                            pidD, iolD, iblD);
  k_blk<<<dim3(16, NB), dim3(256), 0, stream>>>(h, pidD, e2D, e2aD, Ublk, Vblk);
  k_emit<<<dim3(16, NB), dim3(256), 0, stream>>>(h, pidD, e2D, e2aD, c1D, c2D,
                                                 iolD, iblD, Ublk, Vblk, out);
}